// Round 13
// baseline (1186.875 us; speedup 1.0000x reference)
//
#include <hip/hip_runtime.h>
#include <hip/hip_cooperative_groups.h>
#include <math.h>

namespace cg = cooperative_groups;

// Problem constants (match reference)
#define N_NODES 50000
#define N_EDGES 800000
#define DFEAT   128
#define MAXNORM (1.0f - 4e-3f)   // (1 - BALL_EPS)/sqrt(c), c=1
#define CAP     64               // padded adjacency slots per row (deg ~ Poisson(16), max ~45)
#define OVF_CAP 8192
#define NPART   8                // row partitions (~XCDs)
#define PSIZE   (N_NODES / NPART) // 6250 rows per partition
#define SENT    N_NODES          // sentinel node id (xb row is zeros)

#define COOP_BLOCKS 2048          // 8 blocks/CU x 256 CUs: exactly co-resident

__device__ __forceinline__ float bf_lo(unsigned int w) { return __uint_as_float(w << 16); }
__device__ __forceinline__ float bf_hi(unsigned int w) { return __uint_as_float(w & 0xFFFF0000u); }

__device__ __forceinline__ unsigned int pack2_bf16(float lo_f, float hi_f) {
    unsigned int lo = __float_as_uint(lo_f);
    unsigned int hi = __float_as_uint(hi_f);
    lo = (lo + 0x7FFFu + ((lo >> 16) & 1u)) >> 16;   // RNE to bf16
    hi = (hi + 0x7FFFu + ((hi >> 16) & 1u)) >> 16;
    return lo | (hi << 16);
}

// ==================== tier 1: single cooperative dispatch ====================
// phase0 zero -> sync -> phase1 partitioned build (XCD-local, r11-proven)
// -> sync -> phase2 prep (pre-scaled bf16 xb) -> sync -> phase3 gather
// (r9-proven 8-neighbor/iter body). One dispatch kills ~3x ~13us overhead.
__global__ __launch_bounds__(256, 8) void k_fused(const float* __restrict__ x,
                                                  const int* __restrict__ row,
                                                  const int* __restrict__ col,
                                                  unsigned int* xb,
                                                  unsigned short* adj16,
                                                  int* deg,
                                                  int* ovf, int* ovf_cnt,
                                                  float* __restrict__ out) {
    cg::grid_group grid = cg::this_grid();
    const int tid = blockIdx.x * blockDim.x + threadIdx.x;
    const int nthreads = gridDim.x * blockDim.x;

    // ---- phase 0: zero deg + ovf_cnt ----
    for (int i = tid; i < N_NODES; i += nthreads) deg[i] = 0;
    if (tid == 0) *ovf_cnt = 0;
    __threadfence();
    grid.sync();

    // ---- phase 1: partitioned build ----
    {
        int p      = blockIdx.x & (NPART - 1);
        int vblock = blockIdx.x >> 3;
        int stride = (gridDim.x >> 3) * blockDim.x;
        int lo = p * PSIZE, hi = lo + PSIZE;
        for (int i = vblock * blockDim.x + threadIdx.x; i < N_EDGES; i += stride) {
            int r = row[i], c = col[i];
            if (r < lo || r >= hi || r == c) continue;
            int pos = atomicAdd(&deg[r], 1);
            if (pos < CAP) adj16[r * CAP + pos] = (unsigned short)c;
            else {
                int o = atomicAdd(ovf_cnt, 1);
                if (o < OVF_CAP) { ovf[2 * o] = r; ovf[2 * o + 1] = c; }
            }
        }
    }
    __threadfence();
    grid.sync();

    // ---- phase 2: prep  xb[node] = bf16(x[node]*rsqrt(deg+1)); sentinel row zeros ----
    {
        const int nprep = (N_NODES + 1) * (DFEAT / 8);   // 16 threads per row
        for (int t = tid; t < nprep; t += nthreads) {
            int node = t >> 4;
            int part = t & 15;
            unsigned int w[4];
            if (node < N_NODES) {
                float dis = rsqrtf((float)(deg[node] + 1));
                const float4* x4 = (const float4*)(x + (size_t)node * DFEAT + part * 8);
                float4 a = x4[0];
                float4 b = x4[1];
                w[0] = pack2_bf16(a.x * dis, a.y * dis);
                w[1] = pack2_bf16(a.z * dis, a.w * dis);
                w[2] = pack2_bf16(b.x * dis, b.y * dis);
                w[3] = pack2_bf16(b.z * dis, b.w * dis);
            } else {
                w[0] = w[1] = w[2] = w[3] = 0u;
            }
            ((uint4*)xb)[t] = make_uint4(w[0], w[1], w[2], w[3]);
        }
    }
    __threadfence();
    grid.sync();

    // ---- phase 3: gather, one wave per row, grid-stride ----
    {
        const int lane = threadIdx.x & 63;
        const int half = lane >> 5;
        const int fl   = lane & 31;
        const int gw   = tid >> 6;          // global wave id
        const int gnw  = nthreads >> 6;     // total waves
        const unsigned int* xw = xb + 2 * fl;
        const int novf = *ovf_cnt;

        for (int rowi = gw; rowi < N_NODES; rowi += gnw) {
            int cnt    = deg[rowi];
            int capcnt = cnt < CAP ? cnt : CAP;
            int capR   = (capcnt + 7) & ~7;

            int a = SENT;
            if (lane < capcnt) a = (int)adj16[rowi * CAP + lane];

            float acc0 = 0.f, acc1 = 0.f, acc2 = 0.f, acc3 = 0.f;
            for (int nb = 0; nb < capR; nb += 8) {
                int c0 = __shfl(a, nb + 0 + half);
                int c1 = __shfl(a, nb + 2 + half);
                int c2 = __shfl(a, nb + 4 + half);
                int c3 = __shfl(a, nb + 6 + half);
                uint2 v0 = *(const uint2*)(xw + c0 * (DFEAT / 2));
                uint2 v1 = *(const uint2*)(xw + c1 * (DFEAT / 2));
                uint2 v2 = *(const uint2*)(xw + c2 * (DFEAT / 2));
                uint2 v3 = *(const uint2*)(xw + c3 * (DFEAT / 2));
                acc0 += bf_lo(v0.x); acc1 += bf_hi(v0.x); acc2 += bf_lo(v0.y); acc3 += bf_hi(v0.y);
                acc0 += bf_lo(v1.x); acc1 += bf_hi(v1.x); acc2 += bf_lo(v1.y); acc3 += bf_hi(v1.y);
                acc0 += bf_lo(v2.x); acc1 += bf_hi(v2.x); acc2 += bf_lo(v2.y); acc3 += bf_hi(v2.y);
                acc0 += bf_lo(v3.x); acc1 += bf_hi(v3.x); acc2 += bf_lo(v3.y); acc3 += bf_hi(v3.y);
            }

            if (novf > 0 && half == 0) {
                for (int k = 0; k < novf; ++k) {
                    if (ovf[2 * k] == rowi) {
                        uint2 v = *(const uint2*)(xw + ovf[2 * k + 1] * (DFEAT / 2));
                        acc0 += bf_lo(v.x); acc1 += bf_hi(v.x);
                        acc2 += bf_lo(v.y); acc3 += bf_hi(v.y);
                    }
                }
            }

            acc0 += __shfl_xor(acc0, 32);
            acc1 += __shfl_xor(acc1, 32);
            acc2 += __shfl_xor(acc2, 32);
            acc3 += __shfl_xor(acc3, 32);

            uint2 sv = *(const uint2*)(xw + rowi * (DFEAT / 2));
            acc0 += bf_lo(sv.x); acc1 += bf_hi(sv.x);
            acc2 += bf_lo(sv.y); acc3 += bf_hi(sv.y);

            float di = rsqrtf((float)(cnt + 1));
            acc0 *= di; acc1 *= di; acc2 *= di; acc3 *= di;

            float nsq = acc0 * acc0 + acc1 * acc1 + acc2 * acc2 + acc3 * acc3;
            #pragma unroll
            for (int off = 16; off > 0; off >>= 1) nsq += __shfl_xor(nsq, off);

            float un = fmaxf(sqrtf(nsq), 1e-15f);
            float th = tanhf(un);
            float scale = th / un;
            if (th > MAXNORM) scale *= MAXNORM / th;

            if (half == 0) {
                float4 o = make_float4(acc0 * scale, acc1 * scale, acc2 * scale, acc3 * scale);
                *(float4*)(out + (size_t)rowi * DFEAT + 4 * fl) = o;
            }
        }
    }
}

// ==================== tier 2: r12-proven 4-dispatch path (fallback) ====================

__global__ void k_zero(int* __restrict__ deg, int* __restrict__ ovf_cnt, int n) {
    int i = blockIdx.x * blockDim.x + threadIdx.x;
    if (i < n) deg[i] = 0;
    if (i == 0) *ovf_cnt = 0;
}

__global__ void k_build(const int* __restrict__ row, const int* __restrict__ col,
                        int* __restrict__ deg, unsigned short* __restrict__ adj16,
                        int* __restrict__ ovf, int* __restrict__ ovf_cnt, int e) {
    int p      = blockIdx.x & (NPART - 1);
    int vblock = blockIdx.x >> 3;
    int stride = (gridDim.x >> 3) * blockDim.x;
    int lo = p * PSIZE, hi = lo + PSIZE;
    for (int i = vblock * blockDim.x + threadIdx.x; i < e; i += stride) {
        int r = row[i], c = col[i];
        if (r < lo || r >= hi || r == c) continue;
        int pos = atomicAdd(&deg[r], 1);
        if (pos < CAP) adj16[r * CAP + pos] = (unsigned short)c;
        else {
            int o = atomicAdd(ovf_cnt, 1);
            if (o < OVF_CAP) { ovf[2 * o] = r; ovf[2 * o + 1] = c; }
        }
    }
}

__global__ __launch_bounds__(256) void k_prep(const float* __restrict__ x,
                                              const int* __restrict__ deg,
                                              unsigned int* __restrict__ xb,
                                              int nthreads) {
    int t = blockIdx.x * blockDim.x + threadIdx.x;
    if (t >= nthreads) return;
    int node = t >> 4;
    int part = t & 15;
    unsigned int w[4];
    if (node < N_NODES) {
        float dis = rsqrtf((float)(deg[node] + 1));
        const float4* x4 = (const float4*)(x + (size_t)node * DFEAT + part * 8);
        float4 a = x4[0];
        float4 b = x4[1];
        w[0] = pack2_bf16(a.x * dis, a.y * dis);
        w[1] = pack2_bf16(a.z * dis, a.w * dis);
        w[2] = pack2_bf16(b.x * dis, b.y * dis);
        w[3] = pack2_bf16(b.z * dis, b.w * dis);
    } else {
        w[0] = w[1] = w[2] = w[3] = 0u;
    }
    ((uint4*)xb)[t] = make_uint4(w[0], w[1], w[2], w[3]);
}

__global__ __launch_bounds__(256) void k_gather_bf(const unsigned int* __restrict__ xb,
                                                   const unsigned short* __restrict__ adj16,
                                                   const int* __restrict__ deg,
                                                   const int* __restrict__ ovf,
                                                   const int* __restrict__ ovf_cnt,
                                                   float* __restrict__ out, int n) {
    int lane = threadIdx.x & 63;
    int half = lane >> 5;
    int fl   = lane & 31;
    int rowi = blockIdx.x * 4 + (threadIdx.x >> 6);
    if (rowi >= n) return;

    int cnt    = deg[rowi];
    int capcnt = cnt < CAP ? cnt : CAP;
    int capR   = (capcnt + 7) & ~7;

    int a = SENT;
    if (lane < capcnt) a = (int)adj16[rowi * CAP + lane];

    const unsigned int* __restrict__ xw = xb + 2 * fl;

    float acc0 = 0.f, acc1 = 0.f, acc2 = 0.f, acc3 = 0.f;
    for (int nb = 0; nb < capR; nb += 8) {
        int c0 = __shfl(a, nb + 0 + half);
        int c1 = __shfl(a, nb + 2 + half);
        int c2 = __shfl(a, nb + 4 + half);
        int c3 = __shfl(a, nb + 6 + half);
        uint2 v0 = *(const uint2*)(xw + c0 * (DFEAT / 2));
        uint2 v1 = *(const uint2*)(xw + c1 * (DFEAT / 2));
        uint2 v2 = *(const uint2*)(xw + c2 * (DFEAT / 2));
        uint2 v3 = *(const uint2*)(xw + c3 * (DFEAT / 2));
        acc0 += bf_lo(v0.x); acc1 += bf_hi(v0.x); acc2 += bf_lo(v0.y); acc3 += bf_hi(v0.y);
        acc0 += bf_lo(v1.x); acc1 += bf_hi(v1.x); acc2 += bf_lo(v1.y); acc3 += bf_hi(v1.y);
        acc0 += bf_lo(v2.x); acc1 += bf_hi(v2.x); acc2 += bf_lo(v2.y); acc3 += bf_hi(v2.y);
        acc0 += bf_lo(v3.x); acc1 += bf_hi(v3.x); acc2 += bf_lo(v3.y); acc3 += bf_hi(v3.y);
    }

    int novf = *ovf_cnt;
    if (novf > 0 && half == 0) {
        for (int k = 0; k < novf; ++k) {
            if (ovf[2 * k] == rowi) {
                uint2 v = *(const uint2*)(xw + ovf[2 * k + 1] * (DFEAT / 2));
                acc0 += bf_lo(v.x); acc1 += bf_hi(v.x);
                acc2 += bf_lo(v.y); acc3 += bf_hi(v.y);
            }
        }
    }

    acc0 += __shfl_xor(acc0, 32);
    acc1 += __shfl_xor(acc1, 32);
    acc2 += __shfl_xor(acc2, 32);
    acc3 += __shfl_xor(acc3, 32);

    uint2 sv = *(const uint2*)(xw + rowi * (DFEAT / 2));
    acc0 += bf_lo(sv.x); acc1 += bf_hi(sv.x);
    acc2 += bf_lo(sv.y); acc3 += bf_hi(sv.y);

    float di = rsqrtf((float)(cnt + 1));
    acc0 *= di; acc1 *= di; acc2 *= di; acc3 *= di;

    float nsq = acc0 * acc0 + acc1 * acc1 + acc2 * acc2 + acc3 * acc3;
    #pragma unroll
    for (int off = 16; off > 0; off >>= 1) nsq += __shfl_xor(nsq, off);

    float un = fmaxf(sqrtf(nsq), 1e-15f);
    float th = tanhf(un);
    float scale = th / un;
    if (th > MAXNORM) scale *= MAXNORM / th;

    if (half == 0) {
        float4 o = make_float4(acc0 * scale, acc1 * scale, acc2 * scale, acc3 * scale);
        *(float4*)(out + (size_t)rowi * DFEAT + 4 * fl) = o;
    }
}

// ==================== launcher ====================

extern "C" void kernel_launch(void* const* d_in, const int* in_sizes, int n_in,
                              void* d_out, int out_size, void* d_ws, size_t ws_size,
                              hipStream_t stream) {
    const float* x          = (const float*)d_in[0];
    const int*   edge_index = (const int*)d_in[1];
    const int*   row = edge_index;            // [E]
    const int*   col = edge_index + N_EDGES;  // [E]
    float* out = (float*)d_out;
    char*  ws  = (char*)d_ws;

    size_t sz_xb    = sizeof(unsigned short) * (size_t)(N_NODES + 1) * DFEAT;  // 12.80 MB
    size_t sz_adj16 = sizeof(unsigned short) * (size_t)N_NODES * CAP;          //  6.40 MB
    size_t sz_deg   = sizeof(int) * (size_t)N_NODES;
    size_t need = sz_xb + sz_adj16 + sz_deg + sizeof(int) * (1 + 2 * (size_t)OVF_CAP);

    size_t off = 0;
    unsigned int*   xb      = (unsigned int*)(ws + off);   off += sz_xb;
    unsigned short* adj16   = (unsigned short*)(ws + off); off += sz_adj16;
    int*            deg     = (int*)(ws + off);            off += sz_deg;
    int*            ovf_cnt = (int*)(ws + off);            off += sizeof(int);
    int*            ovf     = (int*)(ws + off);

    dim3 blk(256);
    bool coop_ok = false;
    if (ws_size >= need) {
        // tier 1: single cooperative dispatch
        void* args[] = { (void*)&x, (void*)&row, (void*)&col, (void*)&xb, (void*)&adj16,
                         (void*)&deg, (void*)&ovf, (void*)&ovf_cnt, (void*)&out };
        hipError_t err = hipLaunchCooperativeKernel((const void*)k_fused,
                                                    dim3(COOP_BLOCKS), blk, args, 0, stream);
        coop_ok = (err == hipSuccess);
    }

    if (!coop_ok && ws_size >= need) {
        // tier 2: proven r12 4-dispatch path
        int nprep = (N_NODES + 1) * (DFEAT / 8);
        k_zero<<<dim3((N_NODES + 255) / 256), blk, 0, stream>>>(deg, ovf_cnt, N_NODES);
        k_build<<<dim3(8192), blk, 0, stream>>>(row, col, deg, adj16, ovf, ovf_cnt, N_EDGES);
        k_prep<<<dim3((nprep + 255) / 256), blk, 0, stream>>>(x, deg, xb, nprep);
        k_gather_bf<<<dim3((N_NODES + 3) / 4), blk, 0, stream>>>(xb, adj16, deg, ovf, ovf_cnt, out, N_NODES);
    }
}